// Round 13
// baseline (405.921 us; speedup 1.0000x reference)
//
#include <hip/hip_runtime.h>
#include <hip/hip_bf16.h>

#define N_NODES 50000
#define N_EDGES 600000
#define FEA_DIM 128
#define H_DIM 256
#define N_LAYER 3
#define N_GRAPHS 256
#define LABEL_DIM 2

#define SCAN_NB ((N_NODES + 255) / 256)        // 196
#define GEMM_NB ((N_NODES + 63) / 64)          // 782
#define EDGE_NB ((N_EDGES + 255) / 256)        // 2344
#define AGG_NB (((N_NODES + 15) / 16) * 4)     // 12500: 4 feature-quarters x 3125 node-groups

// ---------------- CSR: degree count ----------------

__global__ __launch_bounds__(256) void k_count(const int* __restrict__ dst, int* __restrict__ counts) {
    int e = blockIdx.x * 256 + threadIdx.x;
    if (e < N_EDGES) atomicAdd(&counts[dst[e]], 1);
}

// ---------------- GEMM body (round-9 proven): BM=64, BK=32, 256 thr, 4x8 ----
// A staged transposed [k][m]. Per-output fmac order: k ascending 0..127.

__device__ __forceinline__ void gemm_body(const float* __restrict__ X, const float* __restrict__ W,
                                          float* __restrict__ H, int M, int tile) {
    __shared__ float a_s[32][68];
    __shared__ float b_s[32][128];
    const int tid = threadIdx.x;
    const int row_g = tid >> 4;
    const int col_g = tid & 15;
    const int row_base = tile * 64;
    float acc[4][8] = {};

    for (int kt = 0; kt < 4; ++kt) {
        const int k0 = kt * 32;
#pragma unroll
        for (int j = 0; j < 2; ++j) {
            int id = tid + j * 256;
            int m = id >> 3;
            int kq = (id & 7) << 2;
            float4 v = make_float4(0.f, 0.f, 0.f, 0.f);
            int gr = row_base + m;
            if (gr < M) v = *(const float4*)(X + gr * 128 + k0 + kq);
            a_s[kq + 0][m] = v.x; a_s[kq + 1][m] = v.y;
            a_s[kq + 2][m] = v.z; a_s[kq + 3][m] = v.w;
        }
#pragma unroll
        for (int j = 0; j < 4; ++j) {
            int id = tid + j * 256;
            int k = id >> 5;
            int n = (id & 31) << 2;
            *(float4*)(&b_s[k][n]) = *(const float4*)(W + (k0 + k) * 128 + n);
        }
        __syncthreads();
#pragma unroll 8
        for (int k = 0; k < 32; ++k) {
            float4 a0 = *(const float4*)(&a_s[k][row_g * 4]);
            float4 b0 = *(const float4*)(&b_s[k][col_g * 4]);
            float4 b1 = *(const float4*)(&b_s[k][64 + col_g * 4]);
            float av[4] = {a0.x, a0.y, a0.z, a0.w};
            float bv[8] = {b0.x, b0.y, b0.z, b0.w, b1.x, b1.y, b1.z, b1.w};
#pragma unroll
            for (int i = 0; i < 4; ++i)
#pragma unroll
                for (int jj = 0; jj < 8; ++jj) acc[i][jj] += av[i] * bv[jj];
        }
        __syncthreads();
    }
#pragma unroll
    for (int i = 0; i < 4; ++i) {
        int gr = row_base + row_g * 4 + i;
        if (gr < M) {
            float4 o0 = {acc[i][0], acc[i][1], acc[i][2], acc[i][3]};
            float4 o1 = {acc[i][4], acc[i][5], acc[i][6], acc[i][7]};
            *(float4*)(H + gr * 128 + col_g * 4) = o0;
            *(float4*)(H + gr * 128 + 64 + col_g * 4) = o1;
        }
    }
}

__global__ __launch_bounds__(256) void k_gemm(const float* __restrict__ X, const float* __restrict__ W,
                                              float* __restrict__ H, int M) {
    gemm_body(X, W, H, M, blockIdx.x);
}

// Fused: blocks [0, GEMM_NB) run GEMM layer-0 tiles; blocks [GEMM_NB, ...) do
// CSR fill. Independent works.
__global__ __launch_bounds__(256) void k_gemm0_fill(const float* __restrict__ X, const float* __restrict__ W,
                                                    float* __restrict__ H,
                                                    const int* __restrict__ src, const int* __restrict__ dst,
                                                    const int* __restrict__ row_ptr, int* __restrict__ cursor,
                                                    int* __restrict__ col) {
    if (blockIdx.x < GEMM_NB) {
        gemm_body(X, W, H, N_NODES, blockIdx.x);
    } else {
        int e = (blockIdx.x - GEMM_NB) * 256 + threadIdx.x;
        if (e < N_EDGES) {
            int s = src[e], d = dst[e];
            int p = row_ptr[d] + atomicAdd(&cursor[d], 1);
            col[p] = s;
        }
    }
}

// ---------------- CSR row_ptr: fused partial+scan ----------------
// Each block redundantly computes the 196 chunk-sums (wave-reduce over the
// L2-resident counts array), scans them in LDS, then does its block-local
// scan. Replaces the separate k_partial dispatch.

__global__ __launch_bounds__(256) void k_rowptr(const int* __restrict__ counts,
                                                int* __restrict__ row_ptr, float* __restrict__ dinv,
                                                int* __restrict__ cursor) {
    __shared__ int sp[256];
    __shared__ int s[256];
    const int tid = threadIdx.x;
    const int lane = tid & 63, wid = tid >> 6;
    // redundant chunk partials: wave `wid` covers chunks wid, wid+4, ...
    for (int j = wid; j < SCAN_NB; j += 4) {
        int i0 = j * 256 + lane * 4;
        int v = 0;
#pragma unroll
        for (int e = 0; e < 4; ++e) {
            int ii = i0 + e;
            if (ii < N_NODES) v += counts[ii];
        }
#pragma unroll
        for (int off = 32; off > 0; off >>= 1) v += __shfl_down(v, off);
        if (lane == 0) sp[j] = v;
    }
    if (tid >= SCAN_NB) sp[tid] = 0;
    __syncthreads();
#pragma unroll
    for (int off = 1; off < 256; off <<= 1) {
        int t = (tid >= off) ? sp[tid - off] : 0;
        __syncthreads();
        sp[tid] += t;
        __syncthreads();
    }
    int block_off = (blockIdx.x == 0) ? 0 : sp[blockIdx.x - 1];

    int g = blockIdx.x * 256 + tid;
    int c = (g < N_NODES) ? counts[g] : 0;
    s[tid] = c;
    __syncthreads();
#pragma unroll
    for (int off = 1; off < 256; off <<= 1) {
        int t = (tid >= off) ? s[tid - off] : 0;
        __syncthreads();
        s[tid] += t;
        __syncthreads();
    }
    if (g < N_NODES) {
        row_ptr[g] = block_off + s[tid] - c;            // exclusive
        dinv[g] = rsqrtf((float)c + 1.0f);              // +1 = self loop
        cursor[g] = 0;
    }
    if (blockIdx.x == 0 && tid == 0) row_ptr[N_NODES] = sp[SCAN_NB - 1];
}

// ---------------- Aggregation: XCD-aware feature QUARTER split ----------------
// blockIdx%8 -> XCD (round-robin), quarter = blockIdx&3: each XCD's L2 only
// caches 1 of the 4 cache lines per H row (50k-line / 6.4MB footprint, ~6x
// reuse). Block: 16 units x 16 lanes; unit = one node's 32-feature quarter
// (float2/lane, one full cache line per gather). Per-output fmac order
// unchanged: self-loop, then CSR edges strictly ascending (batch-of-8
// prefetch) — bitwise identical to prior rounds.

__global__ __launch_bounds__(256) void k_agg(const float* __restrict__ H, const float* __restrict__ bgl,
                                             const int* __restrict__ row_ptr, const int* __restrict__ col,
                                             const float* __restrict__ dinv,
                                             float* __restrict__ Xo) {
    const int b = blockIdx.x;
    const int q = b & 3;                          // feature quarter (XCD mapping)
    const int unit = threadIdx.x >> 4;            // 0..15
    const int ln = threadIdx.x & 15;
    const int i = (b >> 2) * 16 + unit;           // node id
    if (i >= N_NODES) return;
    const int fo = q * 16 + ln;                   // float2 index within the row
    const float2* H2 = (const float2*)H;
    const float di = dinv[i];
    float2 h = H2[(size_t)i * 64 + fo];
    float2 acc;
    acc.x = h.x * di * di;   // self-loop first
    acc.y = h.y * di * di;
    const int p0 = row_ptr[i], p1 = row_ptr[i + 1];
    for (int base = p0; base < p1; base += 16) {
        int m = p1 - base; if (m > 16) m = 16;
        int sc = 0; float wc = 0.f;
        if (ln < m) { sc = col[base + ln]; wc = dinv[sc] * di; }
        for (int j = 0; j < m; j += 8) {
            int cnt = m - j; if (cnt > 8) cnt = 8;
            float2 hbuf[8]; float wbuf[8];
#pragma unroll
            for (int t = 0; t < 8; ++t) {
                if (t < cnt) {
                    int s = __shfl(sc, j + t, 16);
                    wbuf[t] = __shfl(wc, j + t, 16);
                    hbuf[t] = H2[(size_t)s * 64 + fo];
                }
            }
#pragma unroll
            for (int t = 0; t < 8; ++t) {
                if (t < cnt) {
                    acc.x += hbuf[t].x * wbuf[t];
                    acc.y += hbuf[t].y * wbuf[t];
                }
            }
        }
    }
    float2 bb = ((const float2*)bgl)[fo];
    float2 o;
    o.x = fmaxf(acc.x + bb.x, 0.f);
    o.y = fmaxf(acc.y + bb.y, 0.f);
    ((float2*)Xo)[(size_t)i * 64 + fo] = o;
}

// ---------------- Fused mean pool + MLP head ----------------

__global__ __launch_bounds__(256) void k_poolmlp(const float* __restrict__ X, const int* __restrict__ batch,
                                                 const float* __restrict__ w1, const float* __restrict__ b1,
                                                 const float* __restrict__ w2, const float* __restrict__ b2,
                                                 float* __restrict__ out) {
    __shared__ int s_lo, s_hi;
    __shared__ float red[256];
    __shared__ float xs[128];
    __shared__ float hs[256];
    int g = blockIdx.x, tid = threadIdx.x;
    if (tid == 0) {
        int lo = 0, hi = N_NODES;
        while (lo < hi) { int mid = (lo + hi) >> 1; if (batch[mid] < g) lo = mid + 1; else hi = mid; }
        s_lo = lo;
        int lo2 = lo, hi2 = N_NODES;
        while (lo2 < hi2) { int mid = (lo2 + hi2) >> 1; if (batch[mid] < g + 1) lo2 = mid + 1; else hi2 = mid; }
        s_hi = lo2;
    }
    __syncthreads();
    int lo = s_lo, hi = s_hi;
    int f = tid & 127, half = tid >> 7;
    float acc = 0.f;
    for (int r = lo + half; r < hi; r += 2) acc += X[r * 128 + f];
    red[tid] = acc;
    __syncthreads();
    if (tid < 128) {
        int cnt = hi - lo;
        xs[tid] = (red[tid] + red[tid + 128]) / (float)(cnt > 0 ? cnt : 1);
    }
    __syncthreads();
    float a1 = b1[tid];
#pragma unroll 8
    for (int k = 0; k < 128; ++k) a1 += xs[k] * w1[k * H_DIM + tid];
    hs[tid] = fmaxf(a1, 0.f);
    __syncthreads();
    int j = tid >> 7, t2 = tid & 127;
    float p = hs[t2] * w2[t2 * LABEL_DIM + j] + hs[t2 + 128] * w2[(t2 + 128) * LABEL_DIM + j];
    red[tid] = p;
    __syncthreads();
    for (int s2 = 64; s2 > 0; s2 >>= 1) {
        if (t2 < s2) red[tid] += red[tid + s2];
        __syncthreads();
    }
    if (t2 == 0) out[g * LABEL_DIM + j] = red[tid] + b2[j];
}

// ---------------- launch ----------------

extern "C" void kernel_launch(void* const* d_in, const int* in_sizes, int n_in,
                              void* d_out, int out_size, void* d_ws, size_t ws_size,
                              hipStream_t stream) {
    const float* x   = (const float*)d_in[0];
    const float* Wg  = (const float*)d_in[1];
    const float* bg  = (const float*)d_in[2];
    const float* w1  = (const float*)d_in[3];
    const float* b1  = (const float*)d_in[4];
    const float* w2  = (const float*)d_in[5];
    const float* b2  = (const float*)d_in[6];
    const int* eidx  = (const int*)d_in[7];
    const int* batch = (const int*)d_in[8];
    float* out = (float*)d_out;

    const int* src = eidx;
    const int* dst = eidx + N_EDGES;

    char* ws = (char*)d_ws;
    size_t off = 0;
    float* A = (float*)(ws + off); off += (size_t)N_NODES * FEA_DIM * 4;
    float* B = (float*)(ws + off); off += (size_t)N_NODES * FEA_DIM * 4;
    int*   col = (int*)(ws + off); off += (size_t)N_EDGES * 4;
    int*   row_ptr = (int*)(ws + off); off += 200704;
    int*   cursor  = (int*)(ws + off); off += 200704;
    int*   counts  = (int*)(ws + off); off += 200704;
    float* dinv    = (float*)(ws + off); off += 200704;

    hipMemsetAsync(counts, 0, 200704, stream);
    k_count<<<EDGE_NB, 256, 0, stream>>>(dst, counts);
    k_rowptr<<<SCAN_NB, 256, 0, stream>>>(counts, row_ptr, dinv, cursor);
    // gemm layer-0 fused with CSR fill (independent works)
    k_gemm0_fill<<<GEMM_NB + EDGE_NB, 256, 0, stream>>>(x, Wg, B, src, dst, row_ptr, cursor, col);

    k_agg<<<AGG_NB, 256, 0, stream>>>(B, bg + 0 * FEA_DIM, row_ptr, col, dinv, A);
    for (int l = 1; l < N_LAYER; ++l) {
        k_gemm<<<GEMM_NB, 256, 0, stream>>>(A, Wg + (size_t)l * FEA_DIM * FEA_DIM, B, N_NODES);
        k_agg<<<AGG_NB, 256, 0, stream>>>(B, bg + (size_t)l * FEA_DIM, row_ptr, col, dinv, A);
    }
    k_poolmlp<<<N_GRAPHS, 256, 0, stream>>>(A, batch, w1, b1, w2, b2, out);
}

// Round 14
// 372.296 us; speedup vs baseline: 1.0903x; 1.0903x over previous
//
#include <hip/hip_runtime.h>
#include <hip/hip_bf16.h>

#define N_NODES 50000
#define N_EDGES 600000
#define FEA_DIM 128
#define H_DIM 256
#define N_LAYER 3
#define N_GRAPHS 256
#define LABEL_DIM 2

#define SCAN_NB ((N_NODES + 255) / 256)        // 196
#define GEMM_NB ((N_NODES + 63) / 64)          // 782
#define EDGE_NB ((N_EDGES + 255) / 256)        // 2344
#define AGG_NB (((N_NODES + 7) / 8) * 2)       // 12500: 2 feature-halves x 6250 node-groups

// ---------------- CSR: degree count ----------------

__global__ __launch_bounds__(256) void k_count(const int* __restrict__ dst, int* __restrict__ counts) {
    int e = blockIdx.x * 256 + threadIdx.x;
    if (e < N_EDGES) atomicAdd(&counts[dst[e]], 1);
}

// ---------------- GEMM body (round-9 proven): BM=64, BK=32, 256 thr, 4x8 ----
// A staged transposed [k][m]. Per-output fmac order: k ascending 0..127.

__device__ __forceinline__ void gemm_body(const float* __restrict__ X, const float* __restrict__ W,
                                          float* __restrict__ H, int M, int tile) {
    __shared__ float a_s[32][68];
    __shared__ float b_s[32][128];
    const int tid = threadIdx.x;
    const int row_g = tid >> 4;
    const int col_g = tid & 15;
    const int row_base = tile * 64;
    float acc[4][8] = {};

    for (int kt = 0; kt < 4; ++kt) {
        const int k0 = kt * 32;
#pragma unroll
        for (int j = 0; j < 2; ++j) {
            int id = tid + j * 256;
            int m = id >> 3;
            int kq = (id & 7) << 2;
            float4 v = make_float4(0.f, 0.f, 0.f, 0.f);
            int gr = row_base + m;
            if (gr < M) v = *(const float4*)(X + gr * 128 + k0 + kq);
            a_s[kq + 0][m] = v.x; a_s[kq + 1][m] = v.y;
            a_s[kq + 2][m] = v.z; a_s[kq + 3][m] = v.w;
        }
#pragma unroll
        for (int j = 0; j < 4; ++j) {
            int id = tid + j * 256;
            int k = id >> 5;
            int n = (id & 31) << 2;
            *(float4*)(&b_s[k][n]) = *(const float4*)(W + (k0 + k) * 128 + n);
        }
        __syncthreads();
#pragma unroll 8
        for (int k = 0; k < 32; ++k) {
            float4 a0 = *(const float4*)(&a_s[k][row_g * 4]);
            float4 b0 = *(const float4*)(&b_s[k][col_g * 4]);
            float4 b1 = *(const float4*)(&b_s[k][64 + col_g * 4]);
            float av[4] = {a0.x, a0.y, a0.z, a0.w};
            float bv[8] = {b0.x, b0.y, b0.z, b0.w, b1.x, b1.y, b1.z, b1.w};
#pragma unroll
            for (int i = 0; i < 4; ++i)
#pragma unroll
                for (int jj = 0; jj < 8; ++jj) acc[i][jj] += av[i] * bv[jj];
        }
        __syncthreads();
    }
#pragma unroll
    for (int i = 0; i < 4; ++i) {
        int gr = row_base + row_g * 4 + i;
        if (gr < M) {
            float4 o0 = {acc[i][0], acc[i][1], acc[i][2], acc[i][3]};
            float4 o1 = {acc[i][4], acc[i][5], acc[i][6], acc[i][7]};
            *(float4*)(H + gr * 128 + col_g * 4) = o0;
            *(float4*)(H + gr * 128 + 64 + col_g * 4) = o1;
        }
    }
}

__global__ __launch_bounds__(256) void k_gemm(const float* __restrict__ X, const float* __restrict__ W,
                                              float* __restrict__ H, int M) {
    gemm_body(X, W, H, M, blockIdx.x);
}

// Fused: blocks [0, GEMM_NB) run GEMM layer-0 tiles; blocks [GEMM_NB, ...) do
// CSR fill. Independent works.
__global__ __launch_bounds__(256) void k_gemm0_fill(const float* __restrict__ X, const float* __restrict__ W,
                                                    float* __restrict__ H,
                                                    const int* __restrict__ src, const int* __restrict__ dst,
                                                    const int* __restrict__ row_ptr, int* __restrict__ cursor,
                                                    int* __restrict__ col) {
    if (blockIdx.x < GEMM_NB) {
        gemm_body(X, W, H, N_NODES, blockIdx.x);
    } else {
        int e = (blockIdx.x - GEMM_NB) * 256 + threadIdx.x;
        if (e < N_EDGES) {
            int s = src[e], d = dst[e];
            int p = row_ptr[d] + atomicAdd(&cursor[d], 1);
            col[p] = s;
        }
    }
}

// ---------------- CSR build (scan phases, round-12 proven) ----------------

__global__ __launch_bounds__(256) void k_partial(const int* __restrict__ counts, int* __restrict__ partial) {
    int g = blockIdx.x * 256 + threadIdx.x;
    int v = (g < N_NODES) ? counts[g] : 0;
#pragma unroll
    for (int off = 32; off > 0; off >>= 1) v += __shfl_down(v, off);
    __shared__ int ws[4];
    int lane = threadIdx.x & 63, wid = threadIdx.x >> 6;
    if (lane == 0) ws[wid] = v;
    __syncthreads();
    if (threadIdx.x == 0) partial[blockIdx.x] = ws[0] + ws[1] + ws[2] + ws[3];
}

__global__ __launch_bounds__(256) void k_rowptr(const int* __restrict__ counts, const int* __restrict__ partial,
                                                int* __restrict__ row_ptr, float* __restrict__ dinv,
                                                int* __restrict__ cursor) {
    __shared__ int sp[256];
    __shared__ int s[256];
    int tid = threadIdx.x;
    sp[tid] = (tid < SCAN_NB) ? partial[tid] : 0;
    __syncthreads();
#pragma unroll
    for (int off = 1; off < 256; off <<= 1) {
        int t = (tid >= off) ? sp[tid - off] : 0;
        __syncthreads();
        sp[tid] += t;
        __syncthreads();
    }
    int block_off = (blockIdx.x == 0) ? 0 : sp[blockIdx.x - 1];

    int g = blockIdx.x * 256 + tid;
    int c = (g < N_NODES) ? counts[g] : 0;
    s[tid] = c;
    __syncthreads();
#pragma unroll
    for (int off = 1; off < 256; off <<= 1) {
        int t = (tid >= off) ? s[tid - off] : 0;
        __syncthreads();
        s[tid] += t;
        __syncthreads();
    }
    if (g < N_NODES) {
        row_ptr[g] = block_off + s[tid] - c;            // exclusive
        dinv[g] = rsqrtf((float)c + 1.0f);              // +1 = self loop
        cursor[g] = 0;
    }
    if (blockIdx.x == 0 && tid == 0) row_ptr[N_NODES] = sp[SCAN_NB - 1];
}

// ---------------- Aggregation: XCD-aware feature HALF split (round-12) ------
// feature half = blockIdx&1 (maps to XCD parity via %8 round-robin). Block:
// 8 half-wave units x 32 lanes; unit = one node's 64-feature half (float2).
// Batch-of-16 prefetch (deeper latency hiding than round 12's 8); accumulate
// strictly ascending -> per-output fmac order bitwise identical.

__global__ __launch_bounds__(256) void k_agg(const float* __restrict__ H, const float* __restrict__ bgl,
                                             const int* __restrict__ row_ptr, const int* __restrict__ col,
                                             const float* __restrict__ dinv,
                                             float* __restrict__ Xo) {
    const int b = blockIdx.x;
    const int half = b & 1;                       // feature half (XCD parity)
    const int unit = threadIdx.x >> 5;            // 0..7
    const int fl = threadIdx.x & 31;
    const int i = (b >> 1) * 8 + unit;            // node id
    if (i >= N_NODES) return;
    const int fo = half * 32 + fl;                // float2 index within the row
    const float2* H2 = (const float2*)H;
    const float di = dinv[i];
    float2 h = H2[(size_t)i * 64 + fo];
    float2 acc;
    acc.x = h.x * di * di;   // self-loop first
    acc.y = h.y * di * di;
    const int p0 = row_ptr[i], p1 = row_ptr[i + 1];
    for (int base = p0; base < p1; base += 32) {
        int m = p1 - base; if (m > 32) m = 32;
        int sc = 0; float wc = 0.f;
        if (fl < m) { sc = col[base + fl]; wc = dinv[sc] * di; }
        for (int j = 0; j < m; j += 16) {
            int cnt = m - j; if (cnt > 16) cnt = 16;
            float2 hbuf[16]; float wbuf[16];
            // phase 1: issue up to 16 independent gathers
#pragma unroll
            for (int t = 0; t < 16; ++t) {
                if (t < cnt) {
                    int s = __shfl(sc, j + t, 32);
                    wbuf[t] = __shfl(wc, j + t, 32);
                    hbuf[t] = H2[(size_t)s * 64 + fo];
                }
            }
            // phase 2: accumulate strictly in ascending edge order
#pragma unroll
            for (int t = 0; t < 16; ++t) {
                if (t < cnt) {
                    acc.x += hbuf[t].x * wbuf[t];
                    acc.y += hbuf[t].y * wbuf[t];
                }
            }
        }
    }
    float2 bb = ((const float2*)bgl)[fo];
    float2 o;
    o.x = fmaxf(acc.x + bb.x, 0.f);
    o.y = fmaxf(acc.y + bb.y, 0.f);
    ((float2*)Xo)[(size_t)i * 64 + fo] = o;
}

// ---------------- Fused mean pool + MLP head ----------------

__global__ __launch_bounds__(256) void k_poolmlp(const float* __restrict__ X, const int* __restrict__ batch,
                                                 const float* __restrict__ w1, const float* __restrict__ b1,
                                                 const float* __restrict__ w2, const float* __restrict__ b2,
                                                 float* __restrict__ out) {
    __shared__ int s_lo, s_hi;
    __shared__ float red[256];
    __shared__ float xs[128];
    __shared__ float hs[256];
    int g = blockIdx.x, tid = threadIdx.x;
    if (tid == 0) {
        int lo = 0, hi = N_NODES;
        while (lo < hi) { int mid = (lo + hi) >> 1; if (batch[mid] < g) lo = mid + 1; else hi = mid; }
        s_lo = lo;
        int lo2 = lo, hi2 = N_NODES;
        while (lo2 < hi2) { int mid = (lo2 + hi2) >> 1; if (batch[mid] < g + 1) lo2 = mid + 1; else hi2 = mid; }
        s_hi = lo2;
    }
    __syncthreads();
    int lo = s_lo, hi = s_hi;
    int f = tid & 127, half = tid >> 7;
    float acc = 0.f;
    for (int r = lo + half; r < hi; r += 2) acc += X[r * 128 + f];
    red[tid] = acc;
    __syncthreads();
    if (tid < 128) {
        int cnt = hi - lo;
        xs[tid] = (red[tid] + red[tid + 128]) / (float)(cnt > 0 ? cnt : 1);
    }
    __syncthreads();
    float a1 = b1[tid];
#pragma unroll 8
    for (int k = 0; k < 128; ++k) a1 += xs[k] * w1[k * H_DIM + tid];
    hs[tid] = fmaxf(a1, 0.f);
    __syncthreads();
    int j = tid >> 7, t2 = tid & 127;
    float p = hs[t2] * w2[t2 * LABEL_DIM + j] + hs[t2 + 128] * w2[(t2 + 128) * LABEL_DIM + j];
    red[tid] = p;
    __syncthreads();
    for (int s2 = 64; s2 > 0; s2 >>= 1) {
        if (t2 < s2) red[tid] += red[tid + s2];
        __syncthreads();
    }
    if (t2 == 0) out[g * LABEL_DIM + j] = red[tid] + b2[j];
}

// ---------------- launch ----------------

extern "C" void kernel_launch(void* const* d_in, const int* in_sizes, int n_in,
                              void* d_out, int out_size, void* d_ws, size_t ws_size,
                              hipStream_t stream) {
    const float* x   = (const float*)d_in[0];
    const float* Wg  = (const float*)d_in[1];
    const float* bg  = (const float*)d_in[2];
    const float* w1  = (const float*)d_in[3];
    const float* b1  = (const float*)d_in[4];
    const float* w2  = (const float*)d_in[5];
    const float* b2  = (const float*)d_in[6];
    const int* eidx  = (const int*)d_in[7];
    const int* batch = (const int*)d_in[8];
    float* out = (float*)d_out;

    const int* src = eidx;
    const int* dst = eidx + N_EDGES;

    char* ws = (char*)d_ws;
    size_t off = 0;
    float* A = (float*)(ws + off); off += (size_t)N_NODES * FEA_DIM * 4;
    float* B = (float*)(ws + off); off += (size_t)N_NODES * FEA_DIM * 4;
    int*   col = (int*)(ws + off); off += (size_t)N_EDGES * 4;
    int*   row_ptr = (int*)(ws + off); off += 200704;
    int*   cursor  = (int*)(ws + off); off += 200704;
    int*   counts  = (int*)(ws + off); off += 200704;
    float* dinv    = (float*)(ws + off); off += 200704;
    int*   partial = (int*)(ws + off); off += 4096;

    hipMemsetAsync(counts, 0, 200704, stream);
    k_count<<<EDGE_NB, 256, 0, stream>>>(dst, counts);
    k_partial<<<SCAN_NB, 256, 0, stream>>>(counts, partial);
    k_rowptr<<<SCAN_NB, 256, 0, stream>>>(counts, partial, row_ptr, dinv, cursor);
    // gemm layer-0 fused with CSR fill (independent works)
    k_gemm0_fill<<<GEMM_NB + EDGE_NB, 256, 0, stream>>>(x, Wg, B, src, dst, row_ptr, cursor, col);

    k_agg<<<AGG_NB, 256, 0, stream>>>(B, bg + 0 * FEA_DIM, row_ptr, col, dinv, A);
    for (int l = 1; l < N_LAYER; ++l) {
        k_gemm<<<GEMM_NB, 256, 0, stream>>>(A, Wg + (size_t)l * FEA_DIM * FEA_DIM, B, N_NODES);
        k_agg<<<AGG_NB, 256, 0, stream>>>(B, bg + (size_t)l * FEA_DIM, row_ptr, col, dinv, A);
    }
    k_poolmlp<<<N_GRAPHS, 256, 0, stream>>>(A, batch, w1, b1, w2, b2, out);
}